// Round 1
// baseline (106.074 us; speedup 1.0000x reference)
//
#include <hip/hip_runtime.h>

#define NCOMP 9                 // component ids 0..8 (0 dropped in epilogue)
#define NB 2                    // batch
#define NBINS (NB * NCOMP * 2)  // {inter, count} per (b, comp) = 36
#define NSLOT 64                // per-lane slots to kill atomic contention
#define SMOOTHF 1e-5f

__global__ void cc_zero(float* __restrict__ ws) {
    int i = threadIdx.x;
    if (i < NBINS) ws[i] = 0.0f;
}

__global__ __launch_bounds__(256) void cc_accum(
        const float* __restrict__ y_pred,
        const int* __restrict__ y,
        const int* __restrict__ comp,
        float* __restrict__ ws,
        int V4, int total4) {
    // bin-major [NBINS][NSLOT]: LDS address = bin*64 + lane -> bank = lane%32,
    // conflict-free for any per-lane component value.
    __shared__ float sacc[NBINS * NSLOT];
    for (int i = threadIdx.x; i < NBINS * NSLOT; i += blockDim.x)
        sacc[i] = 0.0f;
    __syncthreads();

    const int slot = threadIdx.x & 63;
    const int stride = gridDim.x * blockDim.x;

    for (int idx = blockIdx.x * blockDim.x + threadIdx.x; idx < total4; idx += stride) {
        const int b  = (idx >= V4) ? 1 : 0;          // B == 2
        const int v4 = idx - b * V4;
        const long long base = ((long long)b * 2) * ((long long)V4 * 4) + (long long)v4 * 4;

        const float4 a0 = *(const float4*)(y_pred + base);
        const float4 a1 = *(const float4*)(y_pred + base + (long long)V4 * 4);
        const int4 t = ((const int4*)y)[idx];
        const int4 c = ((const int4*)comp)[idx];

        // p_true = softmax(y_pred)[true] = 1 / (1 + exp(t ? (a0-a1) : (a1-a0)))
        {
            float d = a0.x - a1.x;
            float p = 1.0f / (1.0f + __expf(t.x ? d : -d));
            int bb = (b * NCOMP + c.x) * 2;
            atomicAdd(&sacc[bb * NSLOT + slot], p);
            atomicAdd(&sacc[(bb + 1) * NSLOT + slot], 1.0f);
        }
        {
            float d = a0.y - a1.y;
            float p = 1.0f / (1.0f + __expf(t.y ? d : -d));
            int bb = (b * NCOMP + c.y) * 2;
            atomicAdd(&sacc[bb * NSLOT + slot], p);
            atomicAdd(&sacc[(bb + 1) * NSLOT + slot], 1.0f);
        }
        {
            float d = a0.z - a1.z;
            float p = 1.0f / (1.0f + __expf(t.z ? d : -d));
            int bb = (b * NCOMP + c.z) * 2;
            atomicAdd(&sacc[bb * NSLOT + slot], p);
            atomicAdd(&sacc[(bb + 1) * NSLOT + slot], 1.0f);
        }
        {
            float d = a0.w - a1.w;
            float p = 1.0f / (1.0f + __expf(t.w ? d : -d));
            int bb = (b * NCOMP + c.w) * 2;
            atomicAdd(&sacc[bb * NSLOT + slot], p);
            atomicAdd(&sacc[(bb + 1) * NSLOT + slot], 1.0f);
        }
    }
    __syncthreads();

    // 36 bins: one thread per bin sums its 64 slots, one global atomic each.
    for (int bin = threadIdx.x; bin < NBINS; bin += blockDim.x) {
        float s = 0.0f;
        #pragma unroll
        for (int k = 0; k < NSLOT; ++k) s += sacc[bin * NSLOT + k];
        if (s != 0.0f) atomicAdd(&ws[bin], s);
    }
}

__global__ void cc_final(const float* __restrict__ ws, float* __restrict__ out) {
    // psum = tsum = count (softmax sums to 1; one-hot sums to 1).
    float total = 0.0f;
    for (int b = 0; b < NB; ++b) {
        float dsum = 0.0f, pcount = 0.0f;
        for (int k = 1; k < NCOMP; ++k) {   // drop component 0
            float inter = ws[(b * NCOMP + k) * 2 + 0];
            float cnt   = ws[(b * NCOMP + k) * 2 + 1];
            if (cnt > 0.0f) {
                float dice = 1.0f - (2.0f * inter + SMOOTHF) / (2.0f * cnt + SMOOTHF);
                dsum += dice;
                pcount += 1.0f;
            }
        }
        total += dsum / fmaxf(pcount, 1.0f);
    }
    out[0] = total / (float)NB;
}

extern "C" void kernel_launch(void* const* d_in, const int* in_sizes, int n_in,
                              void* d_out, int out_size, void* d_ws, size_t ws_size,
                              hipStream_t stream) {
    const float* y_pred = (const float*)d_in[0];
    const int*   y      = (const int*)d_in[1];
    const int*   comp   = (const int*)d_in[2];
    float* out = (float*)d_out;
    float* ws  = (float*)d_ws;

    const int nvox   = in_sizes[1];   // B * V = 8,192,000
    const int V      = nvox / NB;     // 4,096,000 (divisible by 4)
    const int V4     = V / 4;
    const int total4 = nvox / 4;

    cc_zero<<<dim3(1), dim3(64), 0, stream>>>(ws);

    int blocks = (total4 + 255) / 256;
    if (blocks > 2048) blocks = 2048;
    cc_accum<<<dim3(blocks), dim3(256), 0, stream>>>(y_pred, y, comp, ws, V4, total4);

    cc_final<<<dim3(1), dim3(1), 0, stream>>>(ws, out);
}

// Round 2
// 98.542 us; speedup vs baseline: 1.0764x; 1.0764x over previous
//
#include <hip/hip_runtime.h>

#define NCOMP 9                 // component ids 0..8 (0 dropped in epilogue)
#define NB 2                    // batch
#define NBINS (NB * NCOMP * 2)  // {inter, count} per (b, comp) = 36
#define NSLOT 64                // per-lane slots: LDS atomic addr = bin*64+lane -> 2-way bank alias (free)
#define SMOOTHF 1e-5f
#define MAXBLK 2048

__global__ __launch_bounds__(256) void cc_accum(
        const float* __restrict__ y_pred,
        const int* __restrict__ y,
        const int* __restrict__ comp,
        float* __restrict__ partial,   // [NBINS][nblk], transposed for coalesced reduce
        int V4, int total4, int nblk) {
    __shared__ float sacc[NBINS * NSLOT];
    for (int i = threadIdx.x; i < NBINS * NSLOT; i += blockDim.x)
        sacc[i] = 0.0f;
    __syncthreads();

    const int slot = threadIdx.x & 63;
    const int stride = gridDim.x * blockDim.x;

    for (int idx = blockIdx.x * blockDim.x + threadIdx.x; idx < total4; idx += stride) {
        const int b  = (idx >= V4) ? 1 : 0;          // B == 2
        const int v4 = idx - b * V4;
        const long long base = ((long long)b * 2) * ((long long)V4 * 4) + (long long)v4 * 4;

        const float4 a0 = *(const float4*)(y_pred + base);
        const float4 a1 = *(const float4*)(y_pred + base + (long long)V4 * 4);
        const int4 t = ((const int4*)y)[idx];
        const int4 c = ((const int4*)comp)[idx];

        // p_true = softmax(y_pred)[true] = 1 / (1 + exp(t ? (a0-a1) : (a1-a0)))
        {
            float d = a0.x - a1.x;
            float p = 1.0f / (1.0f + __expf(t.x ? d : -d));
            int bb = (b * NCOMP + c.x) * 2;
            atomicAdd(&sacc[bb * NSLOT + slot], p);
            atomicAdd(&sacc[(bb + 1) * NSLOT + slot], 1.0f);
        }
        {
            float d = a0.y - a1.y;
            float p = 1.0f / (1.0f + __expf(t.y ? d : -d));
            int bb = (b * NCOMP + c.y) * 2;
            atomicAdd(&sacc[bb * NSLOT + slot], p);
            atomicAdd(&sacc[(bb + 1) * NSLOT + slot], 1.0f);
        }
        {
            float d = a0.z - a1.z;
            float p = 1.0f / (1.0f + __expf(t.z ? d : -d));
            int bb = (b * NCOMP + c.z) * 2;
            atomicAdd(&sacc[bb * NSLOT + slot], p);
            atomicAdd(&sacc[(bb + 1) * NSLOT + slot], 1.0f);
        }
        {
            float d = a0.w - a1.w;
            float p = 1.0f / (1.0f + __expf(t.w ? d : -d));
            int bb = (b * NCOMP + c.w) * 2;
            atomicAdd(&sacc[bb * NSLOT + slot], p);
            atomicAdd(&sacc[(bb + 1) * NSLOT + slot], 1.0f);
        }
    }
    __syncthreads();

    // Parallel drain: 8 partial-sums per bin (288 threads), 8-lane shfl tree,
    // one coalesced-column store per bin. NO global atomics.
    const int t = threadIdx.x;
    if (t < NBINS * 8) {
        const int bin = t >> 3, part = t & 7;
        float s = 0.0f;
        #pragma unroll
        for (int k = 0; k < 8; ++k) s += sacc[bin * NSLOT + part * 8 + k];
        s += __shfl_down(s, 4);
        s += __shfl_down(s, 2);
        s += __shfl_down(s, 1);
        if (part == 0) partial[bin * nblk + blockIdx.x] = s;
    }
}

__global__ __launch_bounds__(256) void cc_reduce(
        const float* __restrict__ partial, float* __restrict__ fin, int nblk) {
    const int bin = blockIdx.x;
    float s = 0.0f;
    for (int i = threadIdx.x; i < nblk; i += 256)
        s += partial[bin * nblk + i];
    #pragma unroll
    for (int off = 32; off; off >>= 1) s += __shfl_down(s, off);
    __shared__ float w4[4];
    if ((threadIdx.x & 63) == 0) w4[threadIdx.x >> 6] = s;
    __syncthreads();
    if (threadIdx.x == 0) fin[bin] = w4[0] + w4[1] + w4[2] + w4[3];
}

__global__ void cc_final(const float* __restrict__ fin, float* __restrict__ out) {
    // psum = tsum = count (softmax over 2 ch sums to 1; one-hot sums to 1).
    float total = 0.0f;
    for (int b = 0; b < NB; ++b) {
        float dsum = 0.0f, pcount = 0.0f;
        for (int k = 1; k < NCOMP; ++k) {   // drop component 0
            float inter = fin[(b * NCOMP + k) * 2 + 0];
            float cnt   = fin[(b * NCOMP + k) * 2 + 1];
            if (cnt > 0.0f) {
                float dice = 1.0f - (2.0f * inter + SMOOTHF) / (2.0f * cnt + SMOOTHF);
                dsum += dice;
                pcount += 1.0f;
            }
        }
        total += dsum / fmaxf(pcount, 1.0f);
    }
    out[0] = total / (float)NB;
}

extern "C" void kernel_launch(void* const* d_in, const int* in_sizes, int n_in,
                              void* d_out, int out_size, void* d_ws, size_t ws_size,
                              hipStream_t stream) {
    const float* y_pred = (const float*)d_in[0];
    const int*   y      = (const int*)d_in[1];
    const int*   comp   = (const int*)d_in[2];
    float* out = (float*)d_out;
    float* ws  = (float*)d_ws;

    const int nvox   = in_sizes[1];   // B * V = 8,192,000
    const int V      = nvox / NB;     // 4,096,000
    const int V4     = V / 4;
    const int total4 = nvox / 4;

    // ws layout: partial[NBINS*nblk] | fin[NBINS]
    int cap = (int)((ws_size / sizeof(float) - NBINS) / NBINS);
    int nblk = MAXBLK;
    if (nblk > cap) nblk = cap;
    if (nblk < 1) nblk = 1;
    int need = (total4 + 255) / 256;
    if (nblk > need) nblk = need;

    float* fin = ws + (size_t)NBINS * nblk;

    cc_accum<<<dim3(nblk), dim3(256), 0, stream>>>(y_pred, y, comp, ws, V4, total4, nblk);
    cc_reduce<<<dim3(NBINS), dim3(256), 0, stream>>>(ws, fin, nblk);
    cc_final<<<dim3(1), dim3(1), 0, stream>>>(fin, out);
}

// Round 3
// 33.969 us; speedup vs baseline: 3.1227x; 2.9009x over previous
//
#include <hip/hip_runtime.h>

#define NB 2
#define NCK 8                    // tracked components 1..8 (comp 0 is dropped in epilogue)
#define NVAL (NCK * 2)           // 16 values per (block): {inter,count} x 8
#define NBINS (NB * NVAL)        // 32 global bins
#define SMOOTHF 1e-5f
#define MAXBLK 2048

__global__ __launch_bounds__(256) void cc_accum(
        const float* __restrict__ y_pred,
        const int* __restrict__ y,
        const int* __restrict__ comp,
        float* __restrict__ partial,   // [NBINS][nblk], column = global blockIdx
        int V4, int half, int nblk) {
    const int b   = (blockIdx.x >= half) ? 1 : 0;   // batch is block-uniform
    const int blk = blockIdx.x - b * half;
    const int stride = half * 256;

    float acc[NVAL];               // registers only — no LDS in hot loop
    #pragma unroll
    for (int i = 0; i < NVAL; ++i) acc[i] = 0.0f;

    const float* p0 = y_pred + (long long)b * 2 * ((long long)V4 * 4);
    const float* p1 = p0 + (long long)V4 * 4;
    const int4* yq = (const int4*)y    + (long long)b * V4;
    const int4* cq = (const int4*)comp + (long long)b * V4;

    for (int v = blk * 256 + threadIdx.x; v < V4; v += stride) {
        const float4 a0 = *(const float4*)(p0 + (long long)v * 4);
        const float4 a1 = *(const float4*)(p1 + (long long)v * 4);
        const int4 t = yq[v];
        const int4 c = cq[v];

        // p_true = softmax over 2 channels at the true class = 1/(1+exp(±(a0-a1)))
        {
            float d = a0.x - a1.x;
            float p = 1.0f / (1.0f + __expf(t.x ? d : -d));
            #pragma unroll
            for (int j = 0; j < NCK; ++j) {
                float m = (c.x == j + 1) ? 1.0f : 0.0f;
                acc[2 * j] = fmaf(m, p, acc[2 * j]);
                acc[2 * j + 1] += m;
            }
        }
        {
            float d = a0.y - a1.y;
            float p = 1.0f / (1.0f + __expf(t.y ? d : -d));
            #pragma unroll
            for (int j = 0; j < NCK; ++j) {
                float m = (c.y == j + 1) ? 1.0f : 0.0f;
                acc[2 * j] = fmaf(m, p, acc[2 * j]);
                acc[2 * j + 1] += m;
            }
        }
        {
            float d = a0.z - a1.z;
            float p = 1.0f / (1.0f + __expf(t.z ? d : -d));
            #pragma unroll
            for (int j = 0; j < NCK; ++j) {
                float m = (c.z == j + 1) ? 1.0f : 0.0f;
                acc[2 * j] = fmaf(m, p, acc[2 * j]);
                acc[2 * j + 1] += m;
            }
        }
        {
            float d = a0.w - a1.w;
            float p = 1.0f / (1.0f + __expf(t.w ? d : -d));
            #pragma unroll
            for (int j = 0; j < NCK; ++j) {
                float m = (c.w == j + 1) ? 1.0f : 0.0f;
                acc[2 * j] = fmaf(m, p, acc[2 * j]);
                acc[2 * j + 1] += m;
            }
        }
    }

    // Wave butterfly reduce each of the 16 values across 64 lanes.
    #pragma unroll
    for (int i = 0; i < NVAL; ++i) {
        float s = acc[i];
        #pragma unroll
        for (int off = 32; off; off >>= 1) s += __shfl_xor(s, off);
        acc[i] = s;
    }

    // Cross-wave combine (4 waves) via tiny LDS, then one coalesced store row.
    __shared__ float red[4][NVAL];
    const int lane = threadIdx.x & 63, wid = threadIdx.x >> 6;
    if (lane == 0) {
        #pragma unroll
        for (int i = 0; i < NVAL; ++i) red[wid][i] = acc[i];
    }
    __syncthreads();
    if (threadIdx.x < NVAL) {
        float s = red[0][threadIdx.x] + red[1][threadIdx.x] +
                  red[2][threadIdx.x] + red[3][threadIdx.x];
        partial[(size_t)(b * NVAL + threadIdx.x) * nblk + blockIdx.x] = s;
    }
}

__global__ __launch_bounds__(256) void cc_reduce(
        const float* __restrict__ partial, float* __restrict__ fin,
        int half, int nblk) {
    const int bin = blockIdx.x;            // 0..NBINS-1
    const int b = (bin >= NVAL) ? 1 : 0;   // which batch's columns hold data
    const int c0 = b * half;
    float s = 0.0f;
    for (int i = threadIdx.x; i < half; i += 256)
        s += partial[(size_t)bin * nblk + c0 + i];
    #pragma unroll
    for (int off = 32; off; off >>= 1) s += __shfl_xor(s, off);
    __shared__ float w4[4];
    if ((threadIdx.x & 63) == 0) w4[threadIdx.x >> 6] = s;
    __syncthreads();
    if (threadIdx.x == 0) fin[bin] = w4[0] + w4[1] + w4[2] + w4[3];
}

__global__ void cc_final(const float* __restrict__ fin, float* __restrict__ out) {
    // psum = tsum = count (softmax over 2 ch sums to 1; one-hot sums to 1).
    float total = 0.0f;
    for (int b = 0; b < NB; ++b) {
        float dsum = 0.0f, pcount = 0.0f;
        for (int j = 0; j < NCK; ++j) {
            float inter = fin[b * NVAL + 2 * j];
            float cnt   = fin[b * NVAL + 2 * j + 1];
            if (cnt > 0.0f) {
                float dice = 1.0f - (2.0f * inter + SMOOTHF) / (2.0f * cnt + SMOOTHF);
                dsum += dice;
                pcount += 1.0f;
            }
        }
        total += dsum / fmaxf(pcount, 1.0f);
    }
    out[0] = total / (float)NB;
}

extern "C" void kernel_launch(void* const* d_in, const int* in_sizes, int n_in,
                              void* d_out, int out_size, void* d_ws, size_t ws_size,
                              hipStream_t stream) {
    const float* y_pred = (const float*)d_in[0];
    const int*   y      = (const int*)d_in[1];
    const int*   comp   = (const int*)d_in[2];
    float* out = (float*)d_out;
    float* ws  = (float*)d_ws;

    const int nvox = in_sizes[1];    // B * V = 8,192,000
    const int V    = nvox / NB;      // 4,096,000
    const int V4   = V / 4;          // 1,024,000 quads per batch

    // half = blocks per batch
    int half = MAXBLK / 2;
    int need = (V4 + 255) / 256;
    if (half > need) half = need;
    int cap = (int)((ws_size / sizeof(float) - NBINS) / NBINS / 2);  // nblk=2*half rows of NBINS
    if (half > cap) half = cap;
    if (half < 1) half = 1;
    const int nblk = 2 * half;

    float* fin = ws + (size_t)NBINS * nblk;

    cc_accum<<<dim3(nblk), dim3(256), 0, stream>>>(y_pred, y, comp, ws, V4, half, nblk);
    cc_reduce<<<dim3(NBINS), dim3(256), 0, stream>>>(ws, fin, half, nblk);
    cc_final<<<dim3(1), dim3(1), 0, stream>>>(fin, out);
}